// Round 11
// baseline (650.788 us; speedup 1.0000x reference)
//
#include <hip/hip_runtime.h>
#include <hip/hip_bf16.h>

// Sizes (hard-coded from reference): B=32, T=512, D=64, H=64, S=4096, 4H=256, 2H=128
#define T_ 512

typedef __attribute__((ext_vector_type(8))) short short8;
typedef __attribute__((ext_vector_type(4))) float f32x4;

__device__ __forceinline__ float fast_rcp(float x){ return __builtin_amdgcn_rcpf(x); }
__device__ __forceinline__ float sigmoid_f(float x){
  return fast_rcp(1.f + __expf(-x));
}
__device__ __forceinline__ float tanh_f(float x){
  return fmaf(2.f, fast_rcp(1.f + __expf(-2.f*x)), -1.f);
}
__device__ __forceinline__ float gelu_f(float x){
  float u = 0.7978845608028654f*(x + 0.044715f*x*x*x);
  return 0.5f*x*(1.f + tanh_f(u));
}
__device__ __forceinline__ unsigned short bf16_bits(float x){
  __hip_bfloat16 b = __float2bfloat16(x);
  return __builtin_bit_cast(unsigned short, b);
}
__device__ __forceinline__ float bits_f32(unsigned short u){
  return __uint_as_float(((unsigned)u) << 16);
}
// LDS-only barrier: global loads/stores stay in flight across it.
__device__ __forceinline__ void bar_lds(){
  asm volatile("s_waitcnt lgkmcnt(0)\n\ts_barrier" ::: "memory");
}

// -------- Prep 1: enc fp32 [32][512][64] -> encB bf16 hi/lo [512][32][128] --
__global__ __launch_bounds__(256) void k_encT(const float* __restrict__ enc,
                                              unsigned short* __restrict__ encB)
{
  int i = blockIdx.x*256 + threadIdx.x;       // 1,048,576 elements, grid 4096
  int b = i >> 15, t = (i >> 6) & 511, d = i & 63;
  float v = enc[i];
  unsigned short hi = bf16_bits(v);
  float rem = v - bits_f32(hi);
  unsigned short lo = bf16_bits(rem);
  size_t o = (size_t)t*4096 + b*128 + d;
  encB[o]      = hi;
  encB[o + 64] = lo;
}

// -------- Prep 2: WhxT bf16 [256][128]: row j = [Wh[:,j] | Wx[:,j]] ---------
__global__ __launch_bounds__(256) void k_whxT(const float* __restrict__ Wh,
                                              const float* __restrict__ Wx,
                                              unsigned short* __restrict__ WhxT)
{
  int i = blockIdx.x*256 + threadIdx.x;       // 32768 elements, grid 128
  int j = i >> 7, k = i & 127;
  float v = (k < 64) ? Wh[k*256 + j] : Wx[(k - 64)*256 + j];
  WhxT[i] = bf16_bits(v);                     // i == j*128 + k
}

// ---------------- Kernel 2: fused MFMA LSTM, 2 waves/SIMD for TLP -----------
// grid=2 x 512 threads (8 waves = 2/SIMD). Wave-group g2 = tid>>8 runs an
// INDEPENDENT 8-batch recurrence (batches bo..bo+7) in its own Hb slab; the
// two chains interleave on each SIMD so dependency stalls of one wave are
// filled by the other's issue (rounds 7-10 showed the step is latency-bound
// at 1 wave/SIMD: ~900cy of un-hidden MFMA/TRANS/LDS latency per step).
// Within a group: identical to round 10 (2 units/lane via shfl_xor(8),
// x-projection MFMAs in the shadow, enc hi/lo 4-deep prefetch, bar_lds).
__global__ __launch_bounds__(512, 2) void k_lstm(const unsigned short* __restrict__ encB,
                                                 const unsigned short* __restrict__ WhxT,
                                                 const float* __restrict__ bh,
                                                 unsigned short* __restrict__ hsb)
{
  __shared__ __align__(16) unsigned short Hb[2][2][16][72];   // [group][buf]
  int tid = threadIdx.x;
  int g2 = tid >> 8;                   // batch-half group (0: bo.., 1: bo+8..)
  int w = (tid >> 6) & 3, l = tid & 63;
  int m = l & 15, q = l >> 4;
  int mb = m & 7;                      // batch sub-index (rows 8..15 mirror 0..7)
  bool hi = (m >= 8);                  // hi lanes own units col0+2,3 of batch mb
  int bo = blockIdx.x * 16 + g2 * 8;
  int col0 = 16*w + 4*q;

  const short* Wr = (const short*)WhxT;
  short8 ah[4][2], ax[4][2];
#pragma unroll
  for (int g = 0; g < 4; ++g)
#pragma unroll
    for (int kk = 0; kk < 2; ++kk){
      ah[g][kk] = *(const short8*)(Wr + (64*g + 16*w + m)*128 +      kk*32 + q*8);
      ax[g][kk] = *(const short8*)(Wr + (64*g + 16*w + m)*128 + 64 + kk*32 + q*8);
    }
  f32x4 bb[4];
#pragma unroll
  for (int g = 0; g < 4; ++g){
    bb[g][0] = bh[64*g + 16*w + 4*q + 0];
    bb[g][1] = bh[64*g + 16*w + 4*q + 1];
    bb[g][2] = bh[64*g + 16*w + 4*q + 2];
    bb[g][3] = bh[64*g + 16*w + 4*q + 3];
  }

  // zero BOTH groups' buffers fully: rows 8..15 must read as 0 (B-operand)
  for (int i = tid; i < 2304; i += 512) ((unsigned int*)&Hb[0][0][0][0])[i] = 0;

  const unsigned short* encp = encB;
  int em = (bo + mb)*128;              // m>=8 duplicates batch mb (harmless cols)
  unsigned short* hsrow = hsb + ((size_t)(bo + mb)*512)*64 + col0 + (hi ? 2 : 0);

  short8 EA0,EA1,EA2,EA3, EB0,EB1,EB2,EB3, EC0,EC1,EC2,EC3, ED0,ED1,ED2,ED3;
  short8 e0,e1,e2,e3;
  e0 = *(const short8*)(encp + 0*4096 + em      + q*8);
  e1 = *(const short8*)(encp + 0*4096 + em + 32 + q*8);
  e2 = *(const short8*)(encp + 0*4096 + em + 64 + q*8);
  e3 = *(const short8*)(encp + 0*4096 + em + 96 + q*8);
  EB0 = *(const short8*)(encp + 1*4096 + em      + q*8);
  EB1 = *(const short8*)(encp + 1*4096 + em + 32 + q*8);
  EB2 = *(const short8*)(encp + 1*4096 + em + 64 + q*8);
  EB3 = *(const short8*)(encp + 1*4096 + em + 96 + q*8);
  EC0 = *(const short8*)(encp + 2*4096 + em      + q*8);
  EC1 = *(const short8*)(encp + 2*4096 + em + 32 + q*8);
  EC2 = *(const short8*)(encp + 2*4096 + em + 64 + q*8);
  EC3 = *(const short8*)(encp + 2*4096 + em + 96 + q*8);
  ED0 = *(const short8*)(encp + 3*4096 + em      + q*8);
  ED1 = *(const short8*)(encp + 3*4096 + em + 32 + q*8);
  ED2 = *(const short8*)(encp + 3*4096 + em + 64 + q*8);
  ED3 = *(const short8*)(encp + 3*4096 + em + 96 + q*8);

  f32x4 xacc[4];
#pragma unroll
  for (int g = 0; g < 4; ++g){
    f32x4 a = __builtin_amdgcn_mfma_f32_16x16x32_bf16(ax[g][0], e0, bb[g], 0,0,0);
    a = __builtin_amdgcn_mfma_f32_16x16x32_bf16(ax[g][1], e1, a, 0,0,0);
    a = __builtin_amdgcn_mfma_f32_16x16x32_bf16(ax[g][0], e2, a, 0,0,0);
    xacc[g] = __builtin_amdgcn_mfma_f32_16x16x32_bf16(ax[g][1], e3, a, 0,0,0);
  }
  float c0 = 0.f, c1 = 0.f;
  __syncthreads();                     // prologue: full sync once

#define STEP(tt, EU0,EU1,EU2,EU3, EL0,EL1,EL2,EL3)                             \
  {                                                                            \
    const unsigned short* hb = &Hb[g2][(tt) & 1][0][0];                        \
    short8 hv0 = *(const short8*)(hb + m*72 +      q*8);                       \
    short8 hv1 = *(const short8*)(hb + m*72 + 32 + q*8);                       \
    { /* branch-free prefetch: encB is padded by 4 steps */                    \
      const unsigned short* ep = encp + (size_t)((tt)+4)*4096 + em;            \
      EL0 = *(const short8*)(ep +      q*8);                                   \
      EL1 = *(const short8*)(ep + 32 + q*8);                                   \
      EL2 = *(const short8*)(ep + 64 + q*8);                                   \
      EL3 = *(const short8*)(ep + 96 + q*8);                                   \
    }                                                                          \
    f32x4 z0 = __builtin_amdgcn_mfma_f32_16x16x32_bf16(ah[0][0], hv0, xacc[0], 0,0,0); \
    f32x4 z1 = __builtin_amdgcn_mfma_f32_16x16x32_bf16(ah[1][0], hv0, xacc[1], 0,0,0); \
    f32x4 z2 = __builtin_amdgcn_mfma_f32_16x16x32_bf16(ah[2][0], hv0, xacc[2], 0,0,0); \
    f32x4 z3 = __builtin_amdgcn_mfma_f32_16x16x32_bf16(ah[3][0], hv0, xacc[3], 0,0,0); \
    z0 = __builtin_amdgcn_mfma_f32_16x16x32_bf16(ah[0][1], hv1, z0, 0,0,0);    \
    z1 = __builtin_amdgcn_mfma_f32_16x16x32_bf16(ah[1][1], hv1, z1, 0,0,0);    \
    z2 = __builtin_amdgcn_mfma_f32_16x16x32_bf16(ah[2][1], hv1, z2, 0,0,0);    \
    z3 = __builtin_amdgcn_mfma_f32_16x16x32_bf16(ah[3][1], hv1, z3, 0,0,0);    \
    /* redistribute: regs r=2,3 hop to lane+8 (one shfl_xor per gate/reg) */   \
    float i2 = __shfl_xor(z0[2], 8), i3 = __shfl_xor(z0[3], 8);                \
    float f2 = __shfl_xor(z1[2], 8), f3 = __shfl_xor(z1[3], 8);                \
    float g2v = __shfl_xor(z2[2], 8), g3 = __shfl_xor(z2[3], 8);               \
    float o2 = __shfl_xor(z3[2], 8), o3 = __shfl_xor(z3[3], 8);                \
    float zia = hi ? i2 : z0[0], zib = hi ? i3 : z0[1];                        \
    float zfa = hi ? f2 : z1[0], zfb = hi ? f3 : z1[1];                        \
    float zga = hi ? g2v : z2[0], zgb = hi ? g3 : z2[1];                       \
    float zoa = hi ? o2 : z3[0], zob = hi ? o3 : z3[1];                        \
    float h0, h1;                                                              \
    { float si=sigmoid_f(zia), sf=sigmoid_f(zfa);                              \
      float tg=tanh_f(zga),    so=sigmoid_f(zoa);                              \
      c0 = sf*c0 + si*tg; h0 = so*tanh_f(c0); }                                \
    { float si=sigmoid_f(zib), sf=sigmoid_f(zfb);                              \
      float tg=tanh_f(zgb),    so=sigmoid_f(zob);                              \
      c1 = sf*c1 + si*tg; h1 = so*tanh_f(c1); }                                \
    ushort2 hp;                                                                \
    hp.x = bf16_bits(h0); hp.y = bf16_bits(h1);                                \
    *(ushort2*)(&Hb[g2][((tt)+1) & 1][mb][col0 + (hi ? 2 : 0)]) = hp;          \
    *(ushort2*)(hsrow + (size_t)(tt)*64) = hp;                                 \
    xacc[0] = __builtin_amdgcn_mfma_f32_16x16x32_bf16(ax[0][0], EU0, bb[0], 0,0,0); \
    xacc[1] = __builtin_amdgcn_mfma_f32_16x16x32_bf16(ax[1][0], EU0, bb[1], 0,0,0); \
    xacc[2] = __builtin_amdgcn_mfma_f32_16x16x32_bf16(ax[2][0], EU0, bb[2], 0,0,0); \
    xacc[3] = __builtin_amdgcn_mfma_f32_16x16x32_bf16(ax[3][0], EU0, bb[3], 0,0,0); \
    xacc[0] = __builtin_amdgcn_mfma_f32_16x16x32_bf16(ax[0][1], EU1, xacc[0], 0,0,0); \
    xacc[1] = __builtin_amdgcn_mfma_f32_16x16x32_bf16(ax[1][1], EU1, xacc[1], 0,0,0); \
    xacc[2] = __builtin_amdgcn_mfma_f32_16x16x32_bf16(ax[2][1], EU1, xacc[2], 0,0,0); \
    xacc[3] = __builtin_amdgcn_mfma_f32_16x16x32_bf16(ax[3][1], EU1, xacc[3], 0,0,0); \
    xacc[0] = __builtin_amdgcn_mfma_f32_16x16x32_bf16(ax[0][0], EU2, xacc[0], 0,0,0); \
    xacc[1] = __builtin_amdgcn_mfma_f32_16x16x32_bf16(ax[1][0], EU2, xacc[1], 0,0,0); \
    xacc[2] = __builtin_amdgcn_mfma_f32_16x16x32_bf16(ax[2][0], EU2, xacc[2], 0,0,0); \
    xacc[3] = __builtin_amdgcn_mfma_f32_16x16x32_bf16(ax[3][0], EU2, xacc[3], 0,0,0); \
    xacc[0] = __builtin_amdgcn_mfma_f32_16x16x32_bf16(ax[0][1], EU3, xacc[0], 0,0,0); \
    xacc[1] = __builtin_amdgcn_mfma_f32_16x16x32_bf16(ax[1][1], EU3, xacc[1], 0,0,0); \
    xacc[2] = __builtin_amdgcn_mfma_f32_16x16x32_bf16(ax[2][1], EU3, xacc[2], 0,0,0); \
    xacc[3] = __builtin_amdgcn_mfma_f32_16x16x32_bf16(ax[3][1], EU3, xacc[3], 0,0,0); \
    bar_lds();                                                                 \
  }

  for (int t = 0; t < T_; t += 4){
    STEP(t,   EB0,EB1,EB2,EB3, EA0,EA1,EA2,EA3);
    STEP(t+1, EC0,EC1,EC2,EC3, EB0,EB1,EB2,EB3);
    STEP(t+2, ED0,ED1,ED2,ED3, EC0,EC1,EC2,EC3);
    STEP(t+3, EA0,EA1,EA2,EA3, ED0,ED1,ED2,ED3);
  }
#undef STEP
}

// ---------------- Kernel 3: fused MLP (LN+gelu twice), bf16 in/out ----------
__global__ __launch_bounds__(256) void k_mlp(const unsigned short* __restrict__ hsb,
    const float* __restrict__ W1, const float* __restrict__ b1,
    const float* __restrict__ g1, const float* __restrict__ be1,
    const float* __restrict__ W2, const float* __restrict__ b2,
    const float* __restrict__ g2, const float* __restrict__ be2,
    __hip_bfloat16* __restrict__ h2g)
{
  __shared__ __align__(16) float xs[2][64];
  __shared__ __align__(16) float vs[2][128];
  __shared__ float red[2][2][2];
  int tid = threadIdx.x;
  int jj = tid & 127, rg = tid >> 7;
  int lane = tid & 63;
  int whalf = (tid >> 6) & 1;
  float w1c[64], w2c[128];
#pragma unroll
  for (int k = 0; k < 64; ++k) w1c[k] = W1[k*128 + jj];
#pragma unroll
  for (int k = 0; k < 128; ++k) w2c[k] = W2[k*128 + jj];
  float b1j = b1[jj], g1j = g1[jj], be1j = be1[jj];
  float b2j = b2[jj], g2j = g2[jj], be2j = be2[jj];
  int base = blockIdx.x * 64;
  for (int p = 0; p < 32; ++p){
    int r = base + p*2 + rg;
    if (whalf == 0) xs[rg][lane] = bits_f32(hsb[(size_t)r*64 + lane]);
    __syncthreads();
    float a0 = b1j, a1 = 0.f;
    const float4* x4 = (const float4*)xs[rg];
#pragma unroll
    for (int k4 = 0; k4 < 16; ++k4){
      float4 v = x4[k4];
      a0 = fmaf(v.x, w1c[4*k4+0], a0);
      a1 = fmaf(v.y, w1c[4*k4+1], a1);
      a0 = fmaf(v.z, w1c[4*k4+2], a0);
      a1 = fmaf(v.w, w1c[4*k4+3], a1);
    }
    float a = a0 + a1;
    float s1 = a, s2 = a*a;
#pragma unroll
    for (int off = 32; off > 0; off >>= 1){
      s1 += __shfl_xor(s1, off, 64);
      s2 += __shfl_xor(s2, off, 64);
    }
    if (lane == 0){ red[rg][whalf][0] = s1; red[rg][whalf][1] = s2; }
    __syncthreads();
    s1 = red[rg][0][0] + red[rg][1][0];
    s2 = red[rg][0][1] + red[rg][1][1];
    float mean = s1*(1.f/128.f);
    float var  = s2*(1.f/128.f) - mean*mean;
    float rstd = rsqrtf(var + 1e-6f);
    float y = gelu_f((a - mean)*rstd*g1j + be1j);
    vs[rg][jj] = y;
    __syncthreads();
    float c0 = b2j, c1 = 0.f;
    const float4* v4 = (const float4*)vs[rg];
#pragma unroll
    for (int k4 = 0; k4 < 32; ++k4){
      float4 v = v4[k4];
      c0 = fmaf(v.x, w2c[4*k4+0], c0);
      c1 = fmaf(v.y, w2c[4*k4+1], c1);
      c0 = fmaf(v.z, w2c[4*k4+2], c0);
      c1 = fmaf(v.w, w2c[4*k4+3], c1);
    }
    float cc = c0 + c1;
    float t1 = cc, t2 = cc*cc;
#pragma unroll
    for (int off = 32; off > 0; off >>= 1){
      t1 += __shfl_xor(t1, off, 64);
      t2 += __shfl_xor(t2, off, 64);
    }
    if (lane == 0){ red[rg][whalf][0] = t1; red[rg][whalf][1] = t2; }
    __syncthreads();
    t1 = red[rg][0][0] + red[rg][1][0];
    t2 = red[rg][0][1] + red[rg][1][1];
    mean = t1*(1.f/128.f);
    var  = t2*(1.f/128.f) - mean*mean;
    rstd = rsqrtf(var + 1e-6f);
    float z = gelu_f((cc - mean)*rstd*g2j + be2j);
    h2g[(size_t)r*128 + jj] = __float2bfloat16(z);
  }
}

// ---------------- Kernel 3.5: Wo fp32 [128,4096] -> WoT bf16 [4096,128] -----
__global__ __launch_bounds__(256) void k_wot(const float* __restrict__ Wo,
                                             __hip_bfloat16* __restrict__ WoT)
{
  __shared__ __hip_bfloat16 tl[64][130];
  int tid = threadIdx.x;
  int n0 = blockIdx.x * 64;
  for (int idx = tid; idx < 64*128; idx += 256){
    int k = idx >> 6, nl = idx & 63;
    tl[nl][k] = __float2bfloat16(Wo[(size_t)k*4096 + n0 + nl]);
  }
  __syncthreads();
  for (int idx = tid; idx < 64*128; idx += 256){
    int nl = idx >> 7, k = idx & 127;
    WoT[(size_t)(n0 + nl)*128 + k] = tl[nl][k];
  }
}

// ---------------- Kernel 4: out = h2 @ Wo + bo via bf16 MFMA ----------------
__global__ __launch_bounds__(256) void k_out(const __hip_bfloat16* __restrict__ h2g,
                                             const __hip_bfloat16* __restrict__ WoT,
                                             const float* __restrict__ bo,
                                             float* __restrict__ out)
{
  int bid0 = blockIdx.x;                // XCD swizzle: 8 XCDs x 512 contiguous
  int bid = (bid0 & 7)*512 + (bid0 >> 3);
  int Mb = bid >> 5, Nb = bid & 31;
  int tid = threadIdx.x;
  int w = tid >> 6, l = tid & 63;
  int wm = w >> 1, wn = w & 1;
  int m0 = Mb*128 + wm*64, n0 = Nb*128 + wn*64;
  int lr = l & 15, lk = (l >> 4)*8;
  f32x4 acc[4][4] = {};
  const short* A  = (const short*)WoT;
  const short* Bp = (const short*)h2g;
#pragma unroll
  for (int kk = 0; kk < 4; ++kk){
    int ko = kk*32 + lk;
    short8 av[4], bv[4];
#pragma unroll
    for (int i = 0; i < 4; ++i) av[i] = *(const short8*)(A  + (size_t)(n0 + i*16 + lr)*128 + ko);
#pragma unroll
    for (int i = 0; i < 4; ++i) bv[i] = *(const short8*)(Bp + (size_t)(m0 + i*16 + lr)*128 + ko);
#pragma unroll
    for (int fm = 0; fm < 4; ++fm)
#pragma unroll
      for (int fn = 0; fn < 4; ++fn)
        acc[fm][fn] = __builtin_amdgcn_mfma_f32_16x16x32_bf16(av[fn], bv[fm], acc[fm][fn], 0, 0, 0);
  }
  int nb_ = (l >> 4)*4;
#pragma unroll
  for (int fn = 0; fn < 4; ++fn){
    f32x4 bia = *(const f32x4*)(bo + n0 + fn*16 + nb_);
#pragma unroll
    for (int fm = 0; fm < 4; ++fm){
      size_t row = (size_t)(m0 + fm*16 + lr)*4096;
      __builtin_nontemporal_store(acc[fm][fn] + bia, (f32x4*)(out + row + n0 + fn*16 + nb_));
    }
  }
}

extern "C" void kernel_launch(void* const* d_in, const int* in_sizes, int n_in,
                              void* d_out, int out_size, void* d_ws, size_t ws_size,
                              hipStream_t stream)
{
  const float* enc = (const float*)d_in[0];
  const float* Wx  = (const float*)d_in[1];
  const float* Wh  = (const float*)d_in[2];
  const float* bh  = (const float*)d_in[3];
  const float* W1  = (const float*)d_in[4];
  const float* b1  = (const float*)d_in[5];
  const float* g1  = (const float*)d_in[6];
  const float* be1 = (const float*)d_in[7];
  const float* W2  = (const float*)d_in[8];
  const float* b2  = (const float*)d_in[9];
  const float* g2  = (const float*)d_in[10];
  const float* be2 = (const float*)d_in[11];
  const float* Wo  = (const float*)d_in[12];
  const float* bo  = (const float*)d_in[13];
  float* out = (float*)d_out;

  const size_t encB_bytes = (size_t)(512+4)*4096*2; // 4 MiB + 4-step pad
  const size_t whx_bytes  = (size_t)256*128*2;      // 64 KiB
  const size_t hs_bytes   = (size_t)16384*64*2;     // 2 MiB
  const size_t h2_bytes   = (size_t)16384*128*2;    // 4 MiB
  const size_t wt_bytes   = (size_t)4096*128*2;     // 1 MiB
  char* ws = (char*)d_ws;
  unsigned short *encB, *WhxT, *hsb; __hip_bfloat16 *h2g, *WoT;
  if (ws_size >= encB_bytes + whx_bytes + hs_bytes + h2_bytes + wt_bytes){
    encB = (unsigned short*)ws;
    WhxT = (unsigned short*)(ws + encB_bytes);
    hsb  = (unsigned short*)(ws + encB_bytes + whx_bytes);
    h2g  = (__hip_bfloat16*)(ws + encB_bytes + whx_bytes + hs_bytes);
    WoT  = (__hip_bfloat16*)(ws + encB_bytes + whx_bytes + hs_bytes + h2_bytes);
  } else {
    encB = (unsigned short*)d_out;
    WhxT = (unsigned short*)((char*)d_out + encB_bytes);
    hsb  = (unsigned short*)((char*)d_out + encB_bytes + whx_bytes);
    h2g  = (__hip_bfloat16*)ws;
    WoT  = (__hip_bfloat16*)(ws + h2_bytes);
  }

  k_encT<<<4096, 256, 0, stream>>>(enc, encB);
  k_whxT<<<128,  256, 0, stream>>>(Wh, Wx, WhxT);
  k_wot <<<64,   256, 0, stream>>>(Wo, WoT);
  k_lstm<<<2,    512, 0, stream>>>(encB, WhxT, bh, hsb);
  k_mlp <<<256,  256, 0, stream>>>(hsb, W1, b1, g1, be1, W2, b2, g2, be2, h2g);
  k_out <<<4096, 256, 0, stream>>>(h2g, WoT, bo, out);
}

// Round 12
// 456.219 us; speedup vs baseline: 1.4265x; 1.4265x over previous
//
#include <hip/hip_runtime.h>
#include <hip/hip_bf16.h>

// Sizes (hard-coded from reference): B=32, T=512, D=64, H=64, S=4096, 4H=256, 2H=128
#define T_ 512

typedef __attribute__((ext_vector_type(8))) short short8;
typedef __attribute__((ext_vector_type(4))) float f32x4;

__device__ __forceinline__ float fast_rcp(float x){ return __builtin_amdgcn_rcpf(x); }
__device__ __forceinline__ float sigmoid_f(float x){
  return fast_rcp(1.f + __expf(-x));
}
__device__ __forceinline__ float tanh_f(float x){
  return fmaf(2.f, fast_rcp(1.f + __expf(-2.f*x)), -1.f);
}
__device__ __forceinline__ float gelu_f(float x){
  float u = 0.7978845608028654f*(x + 0.044715f*x*x*x);
  return 0.5f*x*(1.f + tanh_f(u));
}
__device__ __forceinline__ unsigned short bf16_bits(float x){
  __hip_bfloat16 b = __float2bfloat16(x);
  return __builtin_bit_cast(unsigned short, b);
}
__device__ __forceinline__ float bits_f32(unsigned short u){
  return __uint_as_float(((unsigned)u) << 16);
}
// LDS-only barrier: global loads/stores stay in flight across it.
__device__ __forceinline__ void bar_lds(){
  asm volatile("s_waitcnt lgkmcnt(0)\n\ts_barrier" ::: "memory");
}

// -------- Prep 1: enc fp32 [32][512][64] -> encB bf16 hi/lo [512][32][128] --
__global__ __launch_bounds__(256) void k_encT(const float* __restrict__ enc,
                                              unsigned short* __restrict__ encB)
{
  int i = blockIdx.x*256 + threadIdx.x;       // 1,048,576 elements, grid 4096
  int b = i >> 15, t = (i >> 6) & 511, d = i & 63;
  float v = enc[i];
  unsigned short hi = bf16_bits(v);
  float rem = v - bits_f32(hi);
  unsigned short lo = bf16_bits(rem);
  size_t o = (size_t)t*4096 + b*128 + d;
  encB[o]      = hi;
  encB[o + 64] = lo;
}

// -------- Prep 2: WhxT bf16 [256][128]: row j = [Wh[:,j] | Wx[:,j]] ---------
__global__ __launch_bounds__(256) void k_whxT(const float* __restrict__ Wh,
                                              const float* __restrict__ Wx,
                                              unsigned short* __restrict__ WhxT)
{
  int i = blockIdx.x*256 + threadIdx.x;       // 32768 elements, grid 128
  int j = i >> 7, k = i & 127;
  float v = (k < 64) ? Wh[k*256 + j] : Wx[(k - 64)*256 + j];
  WhxT[i] = bf16_bits(v);                     // i == j*128 + k
}

// --------- Kernel 2: MFMA LSTM with producer/consumer wave split ------------
// grid=4 x 512 threads (8 waves = 2/SIMD). Waves 0-3 = CONSUMERS (critical
// path: h ds_reads + 8 Wh MFMAs + gate math, as round 10). Waves 4-7 =
// PRODUCERS: compute xacc = bh + Wx.enc (hi/lo bf16, 16 MFMAs) TWO steps
// ahead into a 4-slot LDS ring; they depend only on enc, so they always
// arrive at the barrier early and their issue slots fill the consumer's
// dependency stalls on the shared SIMD (r11 showed 2 waves/SIMD is +24%/CU;
// asymmetric split keeps grid=4 so all 4 chains stay on 4 CUs).
__global__ __launch_bounds__(512, 2) void k_lstm(const unsigned short* __restrict__ encB,
                                                 const unsigned short* __restrict__ WhxT,
                                                 const float* __restrict__ bh,
                                                 unsigned short* __restrict__ hsb)
{
  __shared__ __align__(16) unsigned short Hb[2][16][72];
  __shared__ __align__(16) float xsl[4*4*4*256];   // [slot][wt][gate][lane*4] = 64 KB
  int tid = threadIdx.x;
  int w = tid >> 6, l = tid & 63;
  bool cons = (w < 4);
  int wt = w & 3;                      // tile-wave index (producer partners its consumer)
  int m = l & 15, q = l >> 4;
  int mb = m & 7;                      // batch sub-index (cols 8..15 phantom)
  bool hi = (m >= 8);                  // hi lanes own units col0+2,3 of batch mb
  int bo = blockIdx.x * 8;
  int col0 = 16*wt + 4*q;

  const short* Wr = (const short*)WhxT;
  short8 ah[4][2], ax[4][2];
  f32x4 bb[4];
  if (cons){
#pragma unroll
    for (int g = 0; g < 4; ++g)
#pragma unroll
      for (int kk = 0; kk < 2; ++kk)
        ah[g][kk] = *(const short8*)(Wr + (64*g + 16*wt + m)*128 + kk*32 + q*8);
  } else {
#pragma unroll
    for (int g = 0; g < 4; ++g)
#pragma unroll
      for (int kk = 0; kk < 2; ++kk)
        ax[g][kk] = *(const short8*)(Wr + (64*g + 16*wt + m)*128 + 64 + kk*32 + q*8);
#pragma unroll
    for (int g = 0; g < 4; ++g){
      bb[g][0] = bh[64*g + 16*wt + 4*q + 0];
      bb[g][1] = bh[64*g + 16*wt + 4*q + 1];
      bb[g][2] = bh[64*g + 16*wt + 4*q + 2];
      bb[g][3] = bh[64*g + 16*wt + 4*q + 3];
    }
  }

  for (int i = tid; i < 1152; i += 512) ((unsigned int*)&Hb[0][0][0])[i] = 0;

  const unsigned short* encp = encB;
  int em = (bo + mb)*128;
  unsigned short* hsrow = hsb + ((size_t)(bo + mb)*512)*64 + col0 + (hi ? 2 : 0);

  float c0 = 0.f, c1 = 0.f;
  short8 EA0,EA1,EA2,EA3, EB0,EB1,EB2,EB3;

  if (!cons){
    // prologue: fill ring slots 0 and 1 (for consumer steps t=0,1)
#pragma unroll
    for (int s = 0; s < 2; ++s){
      const unsigned short* ep = encp + (size_t)s*4096 + em;
      short8 e0 = *(const short8*)(ep      + q*8);
      short8 e1 = *(const short8*)(ep + 32 + q*8);
      short8 e2 = *(const short8*)(ep + 64 + q*8);
      short8 e3 = *(const short8*)(ep + 96 + q*8);
#pragma unroll
      for (int g = 0; g < 4; ++g){
        f32x4 a = __builtin_amdgcn_mfma_f32_16x16x32_bf16(ax[g][0], e0, bb[g], 0,0,0);
        a = __builtin_amdgcn_mfma_f32_16x16x32_bf16(ax[g][1], e1, a, 0,0,0);
        a = __builtin_amdgcn_mfma_f32_16x16x32_bf16(ax[g][0], e2, a, 0,0,0);
        a = __builtin_amdgcn_mfma_f32_16x16x32_bf16(ax[g][1], e3, a, 0,0,0);
        *(f32x4*)(xsl + ((s*4 + wt)*4 + g)*256 + l*4) = a;
      }
    }
    EA0 = *(const short8*)(encp + (size_t)2*4096 + em      + q*8);
    EA1 = *(const short8*)(encp + (size_t)2*4096 + em + 32 + q*8);
    EA2 = *(const short8*)(encp + (size_t)2*4096 + em + 64 + q*8);
    EA3 = *(const short8*)(encp + (size_t)2*4096 + em + 96 + q*8);
    EB0 = *(const short8*)(encp + (size_t)3*4096 + em      + q*8);
    EB1 = *(const short8*)(encp + (size_t)3*4096 + em + 32 + q*8);
    EB2 = *(const short8*)(encp + (size_t)3*4096 + em + 64 + q*8);
    EB3 = *(const short8*)(encp + (size_t)3*4096 + em + 96 + q*8);
  }
  __syncthreads();                     // prologue: full sync once

// Consumer sub-step: h reads, 8 MFMAs with xacc C-in from ring, gates, publish
#define CONS_STEP(tt)                                                          \
  {                                                                            \
    const unsigned short* hb = &Hb[(tt) & 1][0][0];                            \
    short8 hv0 = *(const short8*)(hb + m*72 +      q*8);                       \
    short8 hv1 = *(const short8*)(hb + m*72 + 32 + q*8);                       \
    const float* xp = xsl + (((tt) & 3)*4 + wt)*4*256 + l*4;                   \
    f32x4 X0 = *(const f32x4*)(xp        );                                    \
    f32x4 X1 = *(const f32x4*)(xp +  256 );                                    \
    f32x4 X2 = *(const f32x4*)(xp +  512 );                                    \
    f32x4 X3 = *(const f32x4*)(xp +  768 );                                    \
    f32x4 z0 = __builtin_amdgcn_mfma_f32_16x16x32_bf16(ah[0][0], hv0, X0, 0,0,0); \
    f32x4 z1 = __builtin_amdgcn_mfma_f32_16x16x32_bf16(ah[1][0], hv0, X1, 0,0,0); \
    f32x4 z2 = __builtin_amdgcn_mfma_f32_16x16x32_bf16(ah[2][0], hv0, X2, 0,0,0); \
    f32x4 z3 = __builtin_amdgcn_mfma_f32_16x16x32_bf16(ah[3][0], hv0, X3, 0,0,0); \
    z0 = __builtin_amdgcn_mfma_f32_16x16x32_bf16(ah[0][1], hv1, z0, 0,0,0);    \
    z1 = __builtin_amdgcn_mfma_f32_16x16x32_bf16(ah[1][1], hv1, z1, 0,0,0);    \
    z2 = __builtin_amdgcn_mfma_f32_16x16x32_bf16(ah[2][1], hv1, z2, 0,0,0);    \
    z3 = __builtin_amdgcn_mfma_f32_16x16x32_bf16(ah[3][1], hv1, z3, 0,0,0);    \
    float i2 = __shfl_xor(z0[2], 8), i3 = __shfl_xor(z0[3], 8);                \
    float f2 = __shfl_xor(z1[2], 8), f3 = __shfl_xor(z1[3], 8);                \
    float g2v = __shfl_xor(z2[2], 8), g3 = __shfl_xor(z2[3], 8);               \
    float o2 = __shfl_xor(z3[2], 8), o3 = __shfl_xor(z3[3], 8);                \
    float zia = hi ? i2 : z0[0], zib = hi ? i3 : z0[1];                        \
    float zfa = hi ? f2 : z1[0], zfb = hi ? f3 : z1[1];                        \
    float zga = hi ? g2v : z2[0], zgb = hi ? g3 : z2[1];                       \
    float zoa = hi ? o2 : z3[0], zob = hi ? o3 : z3[1];                        \
    float h0, h1;                                                              \
    { float si=sigmoid_f(zia), sf=sigmoid_f(zfa);                              \
      float tg=tanh_f(zga),    so=sigmoid_f(zoa);                              \
      c0 = sf*c0 + si*tg; h0 = so*tanh_f(c0); }                                \
    { float si=sigmoid_f(zib), sf=sigmoid_f(zfb);                              \
      float tg=tanh_f(zgb),    so=sigmoid_f(zob);                              \
      c1 = sf*c1 + si*tg; h1 = so*tanh_f(c1); }                                \
    ushort2 hp;                                                                \
    hp.x = bf16_bits(h0); hp.y = bf16_bits(h1);                                \
    *(ushort2*)(&Hb[((tt)+1) & 1][mb][col0 + (hi ? 2 : 0)]) = hp;              \
    *(ushort2*)(hsrow + (size_t)(tt)*64) = hp;                                 \
  }

// Producer sub-step: 16 MFMAs from E regs (enc for step tt+2) -> ring slot
// (tt+2)&3, then refill E regs with enc(tt+4) (used two sub-steps later).
#define PROD_STEP(tt, E0,E1,E2,E3)                                             \
  {                                                                            \
    f32x4 xa[4];                                                               \
    _Pragma("unroll")                                                          \
    for (int g = 0; g < 4; ++g){                                               \
      f32x4 a = __builtin_amdgcn_mfma_f32_16x16x32_bf16(ax[g][0], E0, bb[g], 0,0,0); \
      a = __builtin_amdgcn_mfma_f32_16x16x32_bf16(ax[g][1], E1, a, 0,0,0);     \
      a = __builtin_amdgcn_mfma_f32_16x16x32_bf16(ax[g][0], E2, a, 0,0,0);     \
      xa[g] = __builtin_amdgcn_mfma_f32_16x16x32_bf16(ax[g][1], E3, a, 0,0,0); \
    }                                                                          \
    float* xp = xsl + ((((tt)+2) & 3)*4 + wt)*4*256 + l*4;                     \
    *(f32x4*)(xp       ) = xa[0];                                              \
    *(f32x4*)(xp +  256) = xa[1];                                              \
    *(f32x4*)(xp +  512) = xa[2];                                              \
    *(f32x4*)(xp +  768) = xa[3];                                              \
    const unsigned short* ep = encp + (size_t)((tt)+4)*4096 + em;              \
    E0 = *(const short8*)(ep      + q*8);                                      \
    E1 = *(const short8*)(ep + 32 + q*8);                                      \
    E2 = *(const short8*)(ep + 64 + q*8);                                      \
    E3 = *(const short8*)(ep + 96 + q*8);                                      \
  }

  for (int t = 0; t < T_; t += 2){
    if (cons) CONS_STEP(t)
    else      PROD_STEP(t, EA0,EA1,EA2,EA3)
    bar_lds();
    if (cons) CONS_STEP(t+1)
    else      PROD_STEP(t+1, EB0,EB1,EB2,EB3)
    bar_lds();
  }
#undef CONS_STEP
#undef PROD_STEP
}

// ---------------- Kernel 3: fused MLP (LN+gelu twice), bf16 in/out ----------
__global__ __launch_bounds__(256) void k_mlp(const unsigned short* __restrict__ hsb,
    const float* __restrict__ W1, const float* __restrict__ b1,
    const float* __restrict__ g1, const float* __restrict__ be1,
    const float* __restrict__ W2, const float* __restrict__ b2,
    const float* __restrict__ g2, const float* __restrict__ be2,
    __hip_bfloat16* __restrict__ h2g)
{
  __shared__ __align__(16) float xs[2][64];
  __shared__ __align__(16) float vs[2][128];
  __shared__ float red[2][2][2];
  int tid = threadIdx.x;
  int jj = tid & 127, rg = tid >> 7;
  int lane = tid & 63;
  int whalf = (tid >> 6) & 1;
  float w1c[64], w2c[128];
#pragma unroll
  for (int k = 0; k < 64; ++k) w1c[k] = W1[k*128 + jj];
#pragma unroll
  for (int k = 0; k < 128; ++k) w2c[k] = W2[k*128 + jj];
  float b1j = b1[jj], g1j = g1[jj], be1j = be1[jj];
  float b2j = b2[jj], g2j = g2[jj], be2j = be2[jj];
  int base = blockIdx.x * 64;
  for (int p = 0; p < 32; ++p){
    int r = base + p*2 + rg;
    if (whalf == 0) xs[rg][lane] = bits_f32(hsb[(size_t)r*64 + lane]);
    __syncthreads();
    float a0 = b1j, a1 = 0.f;
    const float4* x4 = (const float4*)xs[rg];
#pragma unroll
    for (int k4 = 0; k4 < 16; ++k4){
      float4 v = x4[k4];
      a0 = fmaf(v.x, w1c[4*k4+0], a0);
      a1 = fmaf(v.y, w1c[4*k4+1], a1);
      a0 = fmaf(v.z, w1c[4*k4+2], a0);
      a1 = fmaf(v.w, w1c[4*k4+3], a1);
    }
    float a = a0 + a1;
    float s1 = a, s2 = a*a;
#pragma unroll
    for (int off = 32; off > 0; off >>= 1){
      s1 += __shfl_xor(s1, off, 64);
      s2 += __shfl_xor(s2, off, 64);
    }
    if (lane == 0){ red[rg][whalf][0] = s1; red[rg][whalf][1] = s2; }
    __syncthreads();
    s1 = red[rg][0][0] + red[rg][1][0];
    s2 = red[rg][0][1] + red[rg][1][1];
    float mean = s1*(1.f/128.f);
    float var  = s2*(1.f/128.f) - mean*mean;
    float rstd = rsqrtf(var + 1e-6f);
    float y = gelu_f((a - mean)*rstd*g1j + be1j);
    vs[rg][jj] = y;
    __syncthreads();
    float c0 = b2j, c1 = 0.f;
    const float4* v4 = (const float4*)vs[rg];
#pragma unroll
    for (int k4 = 0; k4 < 32; ++k4){
      float4 v = v4[k4];
      c0 = fmaf(v.x, w2c[4*k4+0], c0);
      c1 = fmaf(v.y, w2c[4*k4+1], c1);
      c0 = fmaf(v.z, w2c[4*k4+2], c0);
      c1 = fmaf(v.w, w2c[4*k4+3], c1);
    }
    float cc = c0 + c1;
    float t1 = cc, t2 = cc*cc;
#pragma unroll
    for (int off = 32; off > 0; off >>= 1){
      t1 += __shfl_xor(t1, off, 64);
      t2 += __shfl_xor(t2, off, 64);
    }
    if (lane == 0){ red[rg][whalf][0] = t1; red[rg][whalf][1] = t2; }
    __syncthreads();
    t1 = red[rg][0][0] + red[rg][1][0];
    t2 = red[rg][0][1] + red[rg][1][1];
    mean = t1*(1.f/128.f);
    var  = t2*(1.f/128.f) - mean*mean;
    rstd = rsqrtf(var + 1e-6f);
    float z = gelu_f((cc - mean)*rstd*g2j + be2j);
    h2g[(size_t)r*128 + jj] = __float2bfloat16(z);
  }
}

// ---------------- Kernel 3.5: Wo fp32 [128,4096] -> WoT bf16 [4096,128] -----
__global__ __launch_bounds__(256) void k_wot(const float* __restrict__ Wo,
                                             __hip_bfloat16* __restrict__ WoT)
{
  __shared__ __hip_bfloat16 tl[64][130];
  int tid = threadIdx.x;
  int n0 = blockIdx.x * 64;
  for (int idx = tid; idx < 64*128; idx += 256){
    int k = idx >> 6, nl = idx & 63;
    tl[nl][k] = __float2bfloat16(Wo[(size_t)k*4096 + n0 + nl]);
  }
  __syncthreads();
  for (int idx = tid; idx < 64*128; idx += 256){
    int nl = idx >> 7, k = idx & 127;
    WoT[(size_t)(n0 + nl)*128 + k] = tl[nl][k];
  }
}

// ---------------- Kernel 4: out = h2 @ Wo + bo via bf16 MFMA ----------------
__global__ __launch_bounds__(256) void k_out(const __hip_bfloat16* __restrict__ h2g,
                                             const __hip_bfloat16* __restrict__ WoT,
                                             const float* __restrict__ bo,
                                             float* __restrict__ out)
{
  int bid0 = blockIdx.x;                // XCD swizzle: 8 XCDs x 512 contiguous
  int bid = (bid0 & 7)*512 + (bid0 >> 3);
  int Mb = bid >> 5, Nb = bid & 31;
  int tid = threadIdx.x;
  int w = tid >> 6, l = tid & 63;
  int wm = w >> 1, wn = w & 1;
  int m0 = Mb*128 + wm*64, n0 = Nb*128 + wn*64;
  int lr = l & 15, lk = (l >> 4)*8;
  f32x4 acc[4][4] = {};
  const short* A  = (const short*)WoT;
  const short* Bp = (const short*)h2g;
#pragma unroll
  for (int kk = 0; kk < 4; ++kk){
    int ko = kk*32 + lk;
    short8 av[4], bv[4];
#pragma unroll
    for (int i = 0; i < 4; ++i) av[i] = *(const short8*)(A  + (size_t)(n0 + i*16 + lr)*128 + ko);
#pragma unroll
    for (int i = 0; i < 4; ++i) bv[i] = *(const short8*)(Bp + (size_t)(m0 + i*16 + lr)*128 + ko);
#pragma unroll
    for (int fm = 0; fm < 4; ++fm)
#pragma unroll
      for (int fn = 0; fn < 4; ++fn)
        acc[fm][fn] = __builtin_amdgcn_mfma_f32_16x16x32_bf16(av[fn], bv[fm], acc[fm][fn], 0, 0, 0);
  }
  int nb_ = (l >> 4)*4;
#pragma unroll
  for (int fn = 0; fn < 4; ++fn){
    f32x4 bia = *(const f32x4*)(bo + n0 + fn*16 + nb_);
#pragma unroll
    for (int fm = 0; fm < 4; ++fm){
      size_t row = (size_t)(m0 + fm*16 + lr)*4096;
      __builtin_nontemporal_store(acc[fm][fn] + bia, (f32x4*)(out + row + n0 + fn*16 + nb_));
    }
  }
}

extern "C" void kernel_launch(void* const* d_in, const int* in_sizes, int n_in,
                              void* d_out, int out_size, void* d_ws, size_t ws_size,
                              hipStream_t stream)
{
  const float* enc = (const float*)d_in[0];
  const float* Wx  = (const float*)d_in[1];
  const float* Wh  = (const float*)d_in[2];
  const float* bh  = (const float*)d_in[3];
  const float* W1  = (const float*)d_in[4];
  const float* b1  = (const float*)d_in[5];
  const float* g1  = (const float*)d_in[6];
  const float* be1 = (const float*)d_in[7];
  const float* W2  = (const float*)d_in[8];
  const float* b2  = (const float*)d_in[9];
  const float* g2  = (const float*)d_in[10];
  const float* be2 = (const float*)d_in[11];
  const float* Wo  = (const float*)d_in[12];
  const float* bo  = (const float*)d_in[13];
  float* out = (float*)d_out;

  const size_t encB_bytes = (size_t)(512+8)*4096*2; // 4 MiB + 8-step pad (prefetch t+5)
  const size_t whx_bytes  = (size_t)256*128*2;      // 64 KiB
  const size_t hs_bytes   = (size_t)16384*64*2;     // 2 MiB
  const size_t h2_bytes   = (size_t)16384*128*2;    // 4 MiB
  const size_t wt_bytes   = (size_t)4096*128*2;     // 1 MiB
  char* ws = (char*)d_ws;
  unsigned short *encB, *WhxT, *hsb; __hip_bfloat16 *h2g, *WoT;
  if (ws_size >= encB_bytes + whx_bytes + hs_bytes + h2_bytes + wt_bytes){
    encB = (unsigned short*)ws;
    WhxT = (unsigned short*)(ws + encB_bytes);
    hsb  = (unsigned short*)(ws + encB_bytes + whx_bytes);
    h2g  = (__hip_bfloat16*)(ws + encB_bytes + whx_bytes + hs_bytes);
    WoT  = (__hip_bfloat16*)(ws + encB_bytes + whx_bytes + hs_bytes + h2_bytes);
  } else {
    encB = (unsigned short*)d_out;
    WhxT = (unsigned short*)((char*)d_out + encB_bytes);
    hsb  = (unsigned short*)((char*)d_out + encB_bytes + whx_bytes);
    h2g  = (__hip_bfloat16*)ws;
    WoT  = (__hip_bfloat16*)(ws + h2_bytes);
  }

  k_encT<<<4096, 256, 0, stream>>>(enc, encB);
  k_whxT<<<128,  256, 0, stream>>>(Wh, Wx, WhxT);
  k_wot <<<64,   256, 0, stream>>>(Wo, WoT);
  k_lstm<<<4,    512, 0, stream>>>(encB, WhxT, bh, hsb);
  k_mlp <<<256,  256, 0, stream>>>(hsb, W1, b1, g1, be1, W2, b2, g2, be2, h2g);
  k_out <<<4096, 256, 0, stream>>>(h2g, WoT, bo, out);
}